// Round 2
// baseline (148.196 us; speedup 1.0000x reference)
//
#include <hip/hip_runtime.h>

// DotProductAttention reduced form (verified rounds 1-8, absmax 0.0156):
//   Qeff[q] = 0.7*Q[q-1] + Q[q] + 0.7*Q[q+1]  (zero pad at edges)
//   out[q]  = softmax_{k <= max(q-1,0)}( Qeff[q]·K[k]/8 + beta[k] ) @ V
// Round 10 (resubmit; round-11 bench was an infra failure): attn still
// L2-return-BW bound: round-9 waves (kh x par x qh, 32q x 32k) duplicated every
// frag fetch across the qh pair (270MB L2 reads). New wave shape = 64q x 32k x
// every-4th k-tile (kh x par[0..3]): same frags serve 2x the rows again
// -> 135MB, MFMA count unchanged, still 2048 waves (2/SIMD). Per-tile MFMA per
// wave doubles (16->32) -> better latency cover of the barrier-free prefetch.
// Enablers: beta staged exp-scaled in LDS (frees bt dbuf regs for o[4][4]);
// diagonal mask compile-time specialized (if constexpr) so mask VALU runs only
// on the diagonal tile; 3-barrier 8-way (kh x par) LDS combine (104KB slab,
// 1 blk/CU). Frag store F[hd][tile][frag][lane][8] coalesced by cvt8 (unchanged).
// Permuted key->M-row keeps S^T C-frag == PV B-frag. Fixed-max softmax.

typedef short bf16x8 __attribute__((ext_vector_type(8)));
typedef float f32x4  __attribute__((ext_vector_type(4)));

constexpr int S_ = 2048;
constexpr int D_ = 64;
constexpr float LOG2E = 1.44269504088896341f;
constexpr float KSC = 0.125f * LOG2E;   // 1/sqrt(64), log2 domain

template <bool B> struct BC { static constexpr bool v = B; };

// pack two fp32 -> dword of 2 bf16 (round-half-up), lo in low 16
__device__ __forceinline__ unsigned pk2(float lo, float hi) {
    union { float f; unsigned u; } a, b;
    a.f = lo; b.f = hi;
    return __builtin_amdgcn_perm(b.u + 0x8000u, a.u + 0x8000u, 0x07060302u);
}

// ---- fragment pre-swizzle: F[hd][tile][frag][lane][8] bf16 ----
// frag 0..7  = K A-frags  (kh*4 + mb*2 + hh): lane(n,qd) holds
//              K[key = 64t + 32kh + 8(n>>2) + (n&3) + 4mb][d = 32hh + 8qd .. +8]
// frag 8..15 = V^T A-frags (8 + kh*4 + mb): lane(n,qd) holds
//              V[key = 64t + 32kh + 8qd + j][d = 16mb + n], j = 0..7
__global__ __launch_bounds__(256)
void cvt8(const float* __restrict__ K, const float* __restrict__ V,
          unsigned short* __restrict__ F)
{
    __shared__ float T[64][68];   // V^T fp32: [d][key]

    const int bid = blockIdx.x;            // 512: hd = bid&15 -> XCD bid%8 (matches attn)
    const int hd = bid & 15, tt = bid >> 4;
    const float* Kt = K + ((size_t)hd * S_ + tt * 64) * D_;
    const float* Vt = V + ((size_t)hd * S_ + tt * 64) * D_;
    unsigned short* Ft = F + (size_t)(hd * 32 + tt) * 8192;

    const int t = threadIdx.x;
    const int key = t >> 2, d0 = (t & 3) << 4;

    // ---- V: coalesced read -> transposed LDS ----
    {
        const float* vp = Vt + key * D_ + d0;
        #pragma unroll
        for (int i = 0; i < 4; ++i) {
            float4 v4 = *(const float4*)(vp + 4 * i);
            T[d0 + 4 * i + 0][key] = v4.x;
            T[d0 + 4 * i + 1][key] = v4.y;
            T[d0 + 4 * i + 2][key] = v4.z;
            T[d0 + 4 * i + 3][key] = v4.w;
        }
    }

    // ---- K: coalesced read -> direct frag write ----
    {
        const float* kp = Kt + key * D_ + d0;
        float4 a = *(const float4*)(kp);
        float4 b = *(const float4*)(kp + 4);
        float4 c = *(const float4*)(kp + 8);
        float4 d = *(const float4*)(kp + 12);
        uint4 w0 = make_uint4(pk2(a.x, a.y), pk2(a.z, a.w), pk2(b.x, b.y), pk2(b.z, b.w));
        uint4 w1 = make_uint4(pk2(c.x, c.y), pk2(c.z, c.w), pk2(d.x, d.y), pk2(d.z, d.w));
        const int r5 = key & 31;
        const int kh = key >> 5, mb = (r5 >> 2) & 1;
        const int n = ((r5 >> 3) << 2) | (r5 & 3);       // inverse key->M-row perm
        const int hh = d0 >> 5, qd0 = (d0 >> 3) & 3;
        const int f0 = (kh << 2) | (mb << 1) | hh;
        *(uint4*)(Ft + f0 * 512 + ((qd0 << 4) | n) * 8)       = w0;
        *(uint4*)(Ft + f0 * 512 + (((qd0 + 1) << 4) | n) * 8) = w1;
    }
    __syncthreads();

    // ---- V frag emission: contiguous LDS reads, coalesced 16B writes ----
    #pragma unroll
    for (int s = 0; s < 2; ++s) {
        const int slot = t + s * 256;
        const int fr = slot >> 6, lane = slot & 63;
        const int kh = fr >> 2, mb = fr & 3, n = lane & 15, qd = lane >> 4;
        const float* row = &T[mb * 16 + n][kh * 32 + qd * 8];
        uint4 w = make_uint4(pk2(row[0], row[1]), pk2(row[2], row[3]),
                             pk2(row[4], row[5]), pk2(row[6], row[7]));
        *(uint4*)(Ft + (8 + fr) * 512 + lane * 8) = w;
    }
}

__global__ __launch_bounds__(512, 2)
void attn10(const float* __restrict__ Q, const float* __restrict__ beta,
            const unsigned short* __restrict__ F, float* __restrict__ out)
{
    __shared__ float slab[2][3][64][68];   // [kh][par-1][row][0..63: O, 64: l]
    __shared__ float bl[S_];               // exp-scaled beta (log2 domain)

    const int bid = blockIdx.x;
    const int hd = bid & 15;          // head pinned to XCD bid&7 (2 heads/XCD)
    const int pr = bid >> 4;          // pair index -> q-tiles (pr, 31-pr)

    const float* Qh = Q + (size_t)hd * S_ * D_;
    const unsigned short* Fh = F + (size_t)hd * 32 * 8192;

    const int t = threadIdx.x, lane = t & 63;
    const int wv = t >> 6;
    const int kh = wv & 1, par = wv >> 1;   // par 0..3: every-4th k-tile
    const int n_l = lane & 15, qd = lane >> 4;

    // ---- stage beta*log2e in LDS once (read broadcast by all waves/tiles) ----
    #pragma unroll
    for (int i = 0; i < 4; ++i) bl[t + i * 512] = beta[t + i * 512] * LOG2E;
    __syncthreads();

    // fragment offsets (ushort) within one tile's 8192-ushort block
    const int lo = lane * 8;
    int kfo[2][2], vfo[4];
    #pragma unroll
    for (int mb = 0; mb < 2; ++mb)
        #pragma unroll
        for (int hh = 0; hh < 2; ++hh)
            kfo[mb][hh] = ((kh << 2) | (mb << 1) | hh) * 512 + lo;
    #pragma unroll
    for (int mb = 0; mb < 4; ++mb)
        vfo[mb] = (8 + (kh << 2) + mb) * 512 + lo;

    const int kvo = (kh << 5) + (qd << 3);   // lane's key offset within a tile

    for (int p = 0; p < 2; ++p) {
        const int j = p ? (31 - pr) : pr;
        const int q0 = j << 6;
        const int nt = j + 1;

        auto ld = [&](int tile, bf16x8 (&ka)[2][2], bf16x8 (&vb)[4]) {
            const unsigned short* fp = Fh + (size_t)tile * 8192;
            ka[0][0] = *(const bf16x8*)(fp + kfo[0][0]);
            ka[0][1] = *(const bf16x8*)(fp + kfo[0][1]);
            ka[1][0] = *(const bf16x8*)(fp + kfo[1][0]);
            ka[1][1] = *(const bf16x8*)(fp + kfo[1][1]);
            #pragma unroll
            for (int mb = 0; mb < 4; ++mb)
                vb[mb] = *(const bf16x8*)(fp + vfo[mb]);
        };

        // ---- Qeff B-fragments from global fp32 Q (four q-rows per lane) ----
        bf16x8 qb[4][2];
        #pragma unroll
        for (int ng = 0; ng < 4; ++ng) {
            const int q = q0 + (ng << 4) + n_l;
            const float wp = (q > 0) ? 0.7f : 0.0f;
            const float wn = (q + 1 < S_) ? 0.7f : 0.0f;
            const float* qc = Qh + (size_t)q * D_;
            const float* qpp = qc - ((q > 0) ? D_ : 0);
            const float* qnn = qc + ((q + 1 < S_) ? D_ : 0);
            #pragma unroll
            for (int hh = 0; hh < 2; ++hh) {
                const int d0 = (hh << 5) + (qd << 3);
                float4 c0 = *(const float4*)(qc + d0),  c1 = *(const float4*)(qc + d0 + 4);
                float4 p0 = *(const float4*)(qpp + d0), p1 = *(const float4*)(qpp + d0 + 4);
                float4 n0 = *(const float4*)(qnn + d0), n1 = *(const float4*)(qnn + d0 + 4);
                float e0 = fmaf(wn, n0.x, fmaf(wp, p0.x, c0.x));
                float e1 = fmaf(wn, n0.y, fmaf(wp, p0.y, c0.y));
                float e2 = fmaf(wn, n0.z, fmaf(wp, p0.z, c0.z));
                float e3 = fmaf(wn, n0.w, fmaf(wp, p0.w, c0.w));
                float e4 = fmaf(wn, n1.x, fmaf(wp, p1.x, c1.x));
                float e5 = fmaf(wn, n1.y, fmaf(wp, p1.y, c1.y));
                float e6 = fmaf(wn, n1.z, fmaf(wp, p1.z, c1.z));
                float e7 = fmaf(wn, n1.w, fmaf(wp, p1.w, c1.w));
                union { unsigned u[4]; bf16x8 v; } qu;
                qu.u[0] = pk2(e0, e1); qu.u[1] = pk2(e2, e3);
                qu.u[2] = pk2(e4, e5); qu.u[3] = pk2(e6, e7);
                qb[ng][hh] = qu.v;
            }
        }

        f32x4 o[4][4];
        float l[4] = {0.0f, 0.0f, 0.0f, 0.0f};
        #pragma unroll
        for (int mb = 0; mb < 4; ++mb)
            #pragma unroll
            for (int ng = 0; ng < 4; ++ng) o[mb][ng] = (f32x4){0, 0, 0, 0};

        auto comp = [&](int tile, bf16x8 (&ka)[2][2], bf16x8 (&vb)[4], auto dmc) {
            constexpr bool DM = decltype(dmc)::v;
            const int kb = (tile << 6) + kvo;
            float4 b0 = *(const float4*)&bl[kb];
            float4 b1 = *(const float4*)&bl[kb + 4];
            const float bt[8] = {b0.x, b0.y, b0.z, b0.w, b1.x, b1.y, b1.z, b1.w};
            const f32x4 zz = {0, 0, 0, 0};
            f32x4 acc[2][4];
            #pragma unroll
            for (int mb = 0; mb < 2; ++mb)
                #pragma unroll
                for (int ng = 0; ng < 4; ++ng) {
                    f32x4 a = __builtin_amdgcn_mfma_f32_16x16x32_bf16(ka[mb][0], qb[ng][0], zz, 0, 0, 0);
                    acc[mb][ng] = __builtin_amdgcn_mfma_f32_16x16x32_bf16(ka[mb][1], qb[ng][1], a, 0, 0, 0);
                }
            #pragma unroll
            for (int ng = 0; ng < 4; ++ng) {
                float pv[8];
                float la = 0.0f;
                #pragma unroll
                for (int jj = 0; jj < 8; ++jj) {
                    const int mb = jj >> 2, r = jj & 3;
                    float sv = fmaf(acc[mb][ng][r], KSC, bt[jj]);
                    if constexpr (DM) {
                        const int qr = q0 + (ng << 4) + n_l;
                        const int key = kb + jj;
                        if (!((key < qr) || (qr == 0 && key == 0))) sv = -1.0e30f;
                    }
                    pv[jj] = __builtin_amdgcn_exp2f(sv);
                    la += pv[jj];
                }
                l[ng] += la;
                union { unsigned u[4]; bf16x8 v; } pf;
                pf.u[0] = pk2(pv[0], pv[1]);
                pf.u[1] = pk2(pv[2], pv[3]);
                pf.u[2] = pk2(pv[4], pv[5]);
                pf.u[3] = pk2(pv[6], pv[7]);
                #pragma unroll
                for (int mb = 0; mb < 4; ++mb)
                    o[mb][ng] = __builtin_amdgcn_mfma_f32_16x16x32_bf16(vb[mb], pf.v, o[mb][ng], 0, 0, 0);
            }
        };

        // ---- barrier-free K-loop over this wave's parity class, 2 buffers ----
        bf16x8 kaA[2][2], vbA[4];
        bf16x8 kaB[2][2], vbB[4];
        int it = par;
        if (it < nt) {
            ld(it, kaA, vbA);
            if (it + 4 < nt) ld(it + 4, kaB, vbB);
            while (it + 8 < nt) {
                comp(it, kaA, vbA, BC<false>{});
                ld(it + 8, kaA, vbA);
                comp(it + 4, kaB, vbB, BC<false>{});
                if (it + 12 < nt) ld(it + 12, kaB, vbB);
                it += 8;
            }
            if (it == nt - 1) comp(it, kaA, vbA, BC<true>{});
            else              comp(it, kaA, vbA, BC<false>{});
            if (it + 4 < nt) {
                if (it + 4 == nt - 1) comp(it + 4, kaB, vbB, BC<true>{});
                else                  comp(it + 4, kaB, vbB, BC<false>{});
            }
        }

        // ---- epilogue: quad-reduce l, 3-barrier 8-way (kh x par) combine ----
        #pragma unroll
        for (int ng = 0; ng < 4; ++ng) {
            l[ng] += __shfl_xor(l[ng], 16);
            l[ng] += __shfl_xor(l[ng], 32);
        }
        __syncthreads();   // protects previous pass's final reads
        if (par != 0) {
            const int si = par - 1;
            #pragma unroll
            for (int ng = 0; ng < 4; ++ng) {
                const int row = (ng << 4) + n_l;
                #pragma unroll
                for (int mb = 0; mb < 4; ++mb)
                    *(float4*)&slab[kh][si][row][(mb << 4) + (qd << 2)] =
                        make_float4(o[mb][ng][0], o[mb][ng][1], o[mb][ng][2], o[mb][ng][3]);
                if (qd == 0) slab[kh][si][row][64] = l[ng];
            }
        }
        __syncthreads();
        if (par == 0) {
            #pragma unroll
            for (int ng = 0; ng < 4; ++ng) {
                const int row = (ng << 4) + n_l;
                #pragma unroll
                for (int mb = 0; mb < 4; ++mb) {
                    #pragma unroll
                    for (int si = 0; si < 3; ++si) {
                        float4 pv4 = *(float4*)&slab[kh][si][row][(mb << 4) + (qd << 2)];
                        o[mb][ng][0] += pv4.x; o[mb][ng][1] += pv4.y;
                        o[mb][ng][2] += pv4.z; o[mb][ng][3] += pv4.w;
                    }
                }
                l[ng] += slab[kh][0][row][64] + slab[kh][1][row][64] + slab[kh][2][row][64];
                if (kh == 1) {   // publish kh1 totals (same wave read-then-write, in order)
                    #pragma unroll
                    for (int mb = 0; mb < 4; ++mb)
                        *(float4*)&slab[1][0][row][(mb << 4) + (qd << 2)] =
                            make_float4(o[mb][ng][0], o[mb][ng][1], o[mb][ng][2], o[mb][ng][3]);
                    if (qd == 0) slab[1][0][row][64] = l[ng];
                }
            }
        }
        __syncthreads();
        if (par == 0 && kh == 0) {
            #pragma unroll
            for (int ng = 0; ng < 4; ++ng) {
                const int row = (ng << 4) + n_l;
                const float inv = 1.0f / (l[ng] + slab[1][0][row][64]);
                float* op = out + ((size_t)hd * S_ + q0 + row) * D_ + (qd << 2);
                #pragma unroll
                for (int mb = 0; mb < 4; ++mb) {
                    float4 pv4 = *(float4*)&slab[1][0][row][(mb << 4) + (qd << 2)];
                    *(float4*)(op + (mb << 4)) =
                        make_float4((o[mb][ng][0] + pv4.x) * inv, (o[mb][ng][1] + pv4.y) * inv,
                                    (o[mb][ng][2] + pv4.z) * inv, (o[mb][ng][3] + pv4.w) * inv);
                }
            }
        }
    }
}

extern "C" void kernel_launch(void* const* d_in, const int* in_sizes, int n_in,
                              void* d_out, int out_size, void* d_ws, size_t ws_size,
                              hipStream_t stream) {
    const float* Q    = (const float*)d_in[0];
    const float* K    = (const float*)d_in[1];
    const float* V    = (const float*)d_in[2];
    const float* beta = (const float*)d_in[3];
    // d_in[4]: causal mask (deterministic triu) — handled analytically in-kernel.
    float* out = (float*)d_out;

    unsigned short* F = (unsigned short*)d_ws;   // 16 hd x 32 t x 16 frag x 512 = 8 MB

    cvt8<<<dim3(512), 256, 0, stream>>>(K, V, F);
    attn10<<<dim3(256), 512, 0, stream>>>(Q, beta, F, out);
}

// Round 3
// 128.171 us; speedup vs baseline: 1.1562x; 1.1562x over previous
//
#include <hip/hip_runtime.h>

// DotProductAttention reduced form (verified rounds 1-8, absmax 0.0156):
//   Qeff[q] = 0.7*Q[q-1] + Q[q] + 0.7*Q[q+1]  (zero pad at edges)
//   out[q]  = softmax_{k <= max(q-1,0)}( Qeff[q]·K[k]/8 + beta[k] ) @ V
// Round 12: round-10's 64q waves spilled (VGPR cap 256, demand ~230: 80MB of
// scratch writes, attn 69.5us) and round-9 was never L2-BW bound (1 TB/s/XCD
// vs 4.3 ceiling) -- it was LATENCY-bound at 2 waves/SIMD (grid 256 x 8-wave
// monolithic blocks = 1 block/CU, occupancy 19%). Fix occupancy, keep the
// no-spill round-9 per-wave shape (32q x 32k x every-2nd tile, ~150 VGPR):
//   grid 1024 = head x q-tile x q-half (long tiles first), 256-thr blocks,
//   4 waves (kh x par), __launch_bounds__(256,3) -> 3 blocks/CU = 12 waves/CU.
// LDS 34KB: slab[3][32][68] (kh x par 4-way combine) + exp-scaled beta.
// Barrier-free K-loop per wave; 2 barriers per block total. Diagonal mask
// compile-time specialized. Frag store F[hd][tile][frag][lane][8] by cvt8
// (unchanged). Permuted key->M-row keeps S^T C-frag == PV B-frag.

typedef short bf16x8 __attribute__((ext_vector_type(8)));
typedef float f32x4  __attribute__((ext_vector_type(4)));

constexpr int S_ = 2048;
constexpr int D_ = 64;
constexpr float LOG2E = 1.44269504088896341f;
constexpr float KSC = 0.125f * LOG2E;   // 1/sqrt(64), log2 domain

template <bool B> struct BC { static constexpr bool v = B; };

// pack two fp32 -> dword of 2 bf16 (round-half-up), lo in low 16
__device__ __forceinline__ unsigned pk2(float lo, float hi) {
    union { float f; unsigned u; } a, b;
    a.f = lo; b.f = hi;
    return __builtin_amdgcn_perm(b.u + 0x8000u, a.u + 0x8000u, 0x07060302u);
}

// ---- fragment pre-swizzle: F[hd][tile][frag][lane][8] bf16 ----
// frag 0..7  = K A-frags  (kh*4 + mb*2 + hh): lane(n,qd) holds
//              K[key = 64t + 32kh + 8(n>>2) + (n&3) + 4mb][d = 32hh + 8qd .. +8]
// frag 8..15 = V^T A-frags (8 + kh*4 + mb): lane(n,qd) holds
//              V[key = 64t + 32kh + 8qd + j][d = 16mb + n], j = 0..7
__global__ __launch_bounds__(256)
void cvt8(const float* __restrict__ K, const float* __restrict__ V,
          unsigned short* __restrict__ F)
{
    __shared__ float T[64][68];   // V^T fp32: [d][key]

    const int bid = blockIdx.x;            // 512: hd = bid&15 -> XCD bid%8 (matches attn)
    const int hd = bid & 15, tt = bid >> 4;
    const float* Kt = K + ((size_t)hd * S_ + tt * 64) * D_;
    const float* Vt = V + ((size_t)hd * S_ + tt * 64) * D_;
    unsigned short* Ft = F + (size_t)(hd * 32 + tt) * 8192;

    const int t = threadIdx.x;
    const int key = t >> 2, d0 = (t & 3) << 4;

    // ---- V: coalesced read -> transposed LDS ----
    {
        const float* vp = Vt + key * D_ + d0;
        #pragma unroll
        for (int i = 0; i < 4; ++i) {
            float4 v4 = *(const float4*)(vp + 4 * i);
            T[d0 + 4 * i + 0][key] = v4.x;
            T[d0 + 4 * i + 1][key] = v4.y;
            T[d0 + 4 * i + 2][key] = v4.z;
            T[d0 + 4 * i + 3][key] = v4.w;
        }
    }

    // ---- K: coalesced read -> direct frag write ----
    {
        const float* kp = Kt + key * D_ + d0;
        float4 a = *(const float4*)(kp);
        float4 b = *(const float4*)(kp + 4);
        float4 c = *(const float4*)(kp + 8);
        float4 d = *(const float4*)(kp + 12);
        uint4 w0 = make_uint4(pk2(a.x, a.y), pk2(a.z, a.w), pk2(b.x, b.y), pk2(b.z, b.w));
        uint4 w1 = make_uint4(pk2(c.x, c.y), pk2(c.z, c.w), pk2(d.x, d.y), pk2(d.z, d.w));
        const int r5 = key & 31;
        const int kh = key >> 5, mb = (r5 >> 2) & 1;
        const int n = ((r5 >> 3) << 2) | (r5 & 3);       // inverse key->M-row perm
        const int hh = d0 >> 5, qd0 = (d0 >> 3) & 3;
        const int f0 = (kh << 2) | (mb << 1) | hh;
        *(uint4*)(Ft + f0 * 512 + ((qd0 << 4) | n) * 8)       = w0;
        *(uint4*)(Ft + f0 * 512 + (((qd0 + 1) << 4) | n) * 8) = w1;
    }
    __syncthreads();

    // ---- V frag emission: contiguous LDS reads, coalesced 16B writes ----
    #pragma unroll
    for (int s = 0; s < 2; ++s) {
        const int slot = t + s * 256;
        const int fr = slot >> 6, lane = slot & 63;
        const int kh = fr >> 2, mb = fr & 3, n = lane & 15, qd = lane >> 4;
        const float* row = &T[mb * 16 + n][kh * 32 + qd * 8];
        uint4 w = make_uint4(pk2(row[0], row[1]), pk2(row[2], row[3]),
                             pk2(row[4], row[5]), pk2(row[6], row[7]));
        *(uint4*)(Ft + (8 + fr) * 512 + lane * 8) = w;
    }
}

__global__ __launch_bounds__(256, 3)
void attn12(const float* __restrict__ Q, const float* __restrict__ beta,
            const unsigned short* __restrict__ F, float* __restrict__ out)
{
    __shared__ float slab[3][32][68];   // [wv-1][row][0..63: O, 64: l]
    __shared__ float bl[S_];            // exp-scaled beta (log2 domain)

    const int bid = blockIdx.x;
    const int hd = bid & 15;            // head pinned to XCD bid&7 (2 heads/XCD)
    const int rest = bid >> 4;          // 0..63
    const int j = 31 - (rest >> 1);     // q-tile, longest (j=31) launched first
    const int qh2 = rest & 1;           // which 32-row half of the 64-row tile

    const int q0 = (j << 6) + (qh2 << 5);
    const int nt = j + 1;

    const float* Qh = Q + (size_t)hd * S_ * D_;
    const unsigned short* Fh = F + (size_t)hd * 32 * 8192;

    const int t = threadIdx.x, lane = t & 63;
    const int wv = t >> 6;
    const int kh = wv & 1, par = wv >> 1;   // par 0..1: every-2nd k-tile
    const int n_l = lane & 15, qd = lane >> 4;

    // ---- stage beta*log2e in LDS once (read broadcast by all waves/tiles) ----
    #pragma unroll
    for (int i = 0; i < 8; ++i) bl[t + i * 256] = beta[t + i * 256] * LOG2E;
    __syncthreads();

    // fragment offsets (ushort) within one tile's 8192-ushort block
    const int lo = lane * 8;
    int kfo[2][2], vfo[4];
    #pragma unroll
    for (int mb = 0; mb < 2; ++mb)
        #pragma unroll
        for (int hh = 0; hh < 2; ++hh)
            kfo[mb][hh] = ((kh << 2) | (mb << 1) | hh) * 512 + lo;
    #pragma unroll
    for (int mb = 0; mb < 4; ++mb)
        vfo[mb] = (8 + (kh << 2) + mb) * 512 + lo;

    const int kvo = (kh << 5) + (qd << 3);   // lane's key offset within a tile

    auto ld = [&](int tile, bf16x8 (&ka)[2][2], bf16x8 (&vb)[4]) {
        const unsigned short* fp = Fh + (size_t)tile * 8192;
        ka[0][0] = *(const bf16x8*)(fp + kfo[0][0]);
        ka[0][1] = *(const bf16x8*)(fp + kfo[0][1]);
        ka[1][0] = *(const bf16x8*)(fp + kfo[1][0]);
        ka[1][1] = *(const bf16x8*)(fp + kfo[1][1]);
        #pragma unroll
        for (int mb = 0; mb < 4; ++mb)
            vb[mb] = *(const bf16x8*)(fp + vfo[mb]);
    };

    // ---- Qeff B-fragments from global fp32 Q (two q-rows per lane) ----
    bf16x8 qb[2][2];
    #pragma unroll
    for (int ng = 0; ng < 2; ++ng) {
        const int q = q0 + (ng << 4) + n_l;
        const float wp = (q > 0) ? 0.7f : 0.0f;
        const float wn = (q + 1 < S_) ? 0.7f : 0.0f;
        const float* qc = Qh + (size_t)q * D_;
        const float* qpp = qc - ((q > 0) ? D_ : 0);
        const float* qnn = qc + ((q + 1 < S_) ? D_ : 0);
        #pragma unroll
        for (int hh = 0; hh < 2; ++hh) {
            const int d0 = (hh << 5) + (qd << 3);
            float4 c0 = *(const float4*)(qc + d0),  c1 = *(const float4*)(qc + d0 + 4);
            float4 p0 = *(const float4*)(qpp + d0), p1 = *(const float4*)(qpp + d0 + 4);
            float4 n0 = *(const float4*)(qnn + d0), n1 = *(const float4*)(qnn + d0 + 4);
            float e0 = fmaf(wn, n0.x, fmaf(wp, p0.x, c0.x));
            float e1 = fmaf(wn, n0.y, fmaf(wp, p0.y, c0.y));
            float e2 = fmaf(wn, n0.z, fmaf(wp, p0.z, c0.z));
            float e3 = fmaf(wn, n0.w, fmaf(wp, p0.w, c0.w));
            float e4 = fmaf(wn, n1.x, fmaf(wp, p1.x, c1.x));
            float e5 = fmaf(wn, n1.y, fmaf(wp, p1.y, c1.y));
            float e6 = fmaf(wn, n1.z, fmaf(wp, p1.z, c1.z));
            float e7 = fmaf(wn, n1.w, fmaf(wp, p1.w, c1.w));
            union { unsigned u[4]; bf16x8 v; } qu;
            qu.u[0] = pk2(e0, e1); qu.u[1] = pk2(e2, e3);
            qu.u[2] = pk2(e4, e5); qu.u[3] = pk2(e6, e7);
            qb[ng][hh] = qu.v;
        }
    }

    f32x4 o[4][2];
    float l[2] = {0.0f, 0.0f};
    #pragma unroll
    for (int mb = 0; mb < 4; ++mb)
        #pragma unroll
        for (int ng = 0; ng < 2; ++ng) o[mb][ng] = (f32x4){0, 0, 0, 0};

    auto comp = [&](int tile, bf16x8 (&ka)[2][2], bf16x8 (&vb)[4], auto dmc) {
        constexpr bool DM = decltype(dmc)::v;
        const int kb = (tile << 6) + kvo;
        float4 b0 = *(const float4*)&bl[kb];
        float4 b1 = *(const float4*)&bl[kb + 4];
        const float bt[8] = {b0.x, b0.y, b0.z, b0.w, b1.x, b1.y, b1.z, b1.w};
        const f32x4 zz = {0, 0, 0, 0};
        f32x4 acc[2][2];
        #pragma unroll
        for (int mb = 0; mb < 2; ++mb)
            #pragma unroll
            for (int ng = 0; ng < 2; ++ng) {
                f32x4 a = __builtin_amdgcn_mfma_f32_16x16x32_bf16(ka[mb][0], qb[ng][0], zz, 0, 0, 0);
                acc[mb][ng] = __builtin_amdgcn_mfma_f32_16x16x32_bf16(ka[mb][1], qb[ng][1], a, 0, 0, 0);
            }
        #pragma unroll
        for (int ng = 0; ng < 2; ++ng) {
            float pv[8];
            float la = 0.0f;
            #pragma unroll
            for (int jj = 0; jj < 8; ++jj) {
                const int mb = jj >> 2, r = jj & 3;
                float sv = fmaf(acc[mb][ng][r], KSC, bt[jj]);
                if constexpr (DM) {
                    const int qr = q0 + (ng << 4) + n_l;
                    const int key = kb + jj;
                    if (!((key < qr) || (qr == 0 && key == 0))) sv = -1.0e30f;
                }
                pv[jj] = __builtin_amdgcn_exp2f(sv);
                la += pv[jj];
            }
            l[ng] += la;
            union { unsigned u[4]; bf16x8 v; } pf;
            pf.u[0] = pk2(pv[0], pv[1]);
            pf.u[1] = pk2(pv[2], pv[3]);
            pf.u[2] = pk2(pv[4], pv[5]);
            pf.u[3] = pk2(pv[6], pv[7]);
            #pragma unroll
            for (int mb = 0; mb < 4; ++mb)
                o[mb][ng] = __builtin_amdgcn_mfma_f32_16x16x32_bf16(vb[mb], pf.v, o[mb][ng], 0, 0, 0);
        }
    };

    // ---- barrier-free K-loop over this wave's parity class, 2 buffers ----
    bf16x8 kaA[2][2], vbA[4];
    bf16x8 kaB[2][2], vbB[4];
    int it = par;
    if (it < nt) {
        ld(it, kaA, vbA);
        if (it + 2 < nt) ld(it + 2, kaB, vbB);
        while (it + 4 < nt) {
            comp(it, kaA, vbA, BC<false>{});
            ld(it + 4, kaA, vbA);
            comp(it + 2, kaB, vbB, BC<false>{});
            if (it + 6 < nt) ld(it + 6, kaB, vbB);
            it += 4;
        }
        if (it == nt - 1) comp(it, kaA, vbA, BC<true>{});
        else              comp(it, kaA, vbA, BC<false>{});
        if (it + 2 < nt) {
            if (it + 2 == nt - 1) comp(it + 2, kaB, vbB, BC<true>{});
            else                  comp(it + 2, kaB, vbB, BC<false>{});
        }
    }

    // ---- epilogue: quad-reduce l, 2-barrier 4-way (kh x par) combine ----
    #pragma unroll
    for (int ng = 0; ng < 2; ++ng) {
        l[ng] += __shfl_xor(l[ng], 16);
        l[ng] += __shfl_xor(l[ng], 32);
    }
    if (wv != 0) {
        const int si = wv - 1;
        #pragma unroll
        for (int ng = 0; ng < 2; ++ng) {
            const int row = (ng << 4) + n_l;
            #pragma unroll
            for (int mb = 0; mb < 4; ++mb)
                *(float4*)&slab[si][row][(mb << 4) + (qd << 2)] =
                    make_float4(o[mb][ng][0], o[mb][ng][1], o[mb][ng][2], o[mb][ng][3]);
            if (qd == 0) slab[si][row][64] = l[ng];
        }
    }
    __syncthreads();
    if (wv == 0) {
        #pragma unroll
        for (int ng = 0; ng < 2; ++ng) {
            const int row = (ng << 4) + n_l;
            #pragma unroll
            for (int mb = 0; mb < 4; ++mb) {
                #pragma unroll
                for (int si = 0; si < 3; ++si) {
                    float4 pv4 = *(float4*)&slab[si][row][(mb << 4) + (qd << 2)];
                    o[mb][ng][0] += pv4.x; o[mb][ng][1] += pv4.y;
                    o[mb][ng][2] += pv4.z; o[mb][ng][3] += pv4.w;
                }
            }
            l[ng] += slab[0][row][64] + slab[1][row][64] + slab[2][row][64];
            const float inv = 1.0f / l[ng];
            float* op = out + ((size_t)hd * S_ + q0 + row) * D_ + (qd << 2);
            #pragma unroll
            for (int mb = 0; mb < 4; ++mb)
                *(float4*)(op + (mb << 4)) =
                    make_float4(o[mb][ng][0] * inv, o[mb][ng][1] * inv,
                                o[mb][ng][2] * inv, o[mb][ng][3] * inv);
        }
    }
}

extern "C" void kernel_launch(void* const* d_in, const int* in_sizes, int n_in,
                              void* d_out, int out_size, void* d_ws, size_t ws_size,
                              hipStream_t stream) {
    const float* Q    = (const float*)d_in[0];
    const float* K    = (const float*)d_in[1];
    const float* V    = (const float*)d_in[2];
    const float* beta = (const float*)d_in[3];
    // d_in[4]: causal mask (deterministic triu) — handled analytically in-kernel.
    float* out = (float*)d_out;

    unsigned short* F = (unsigned short*)d_ws;   // 16 hd x 32 t x 16 frag x 512 = 8 MB

    cvt8<<<dim3(512), 256, 0, stream>>>(K, V, F);
    attn12<<<dim3(1024), 256, 0, stream>>>(Q, beta, F, out);
}

// Round 4
// 128.061 us; speedup vs baseline: 1.1572x; 1.0009x over previous
//
#include <hip/hip_runtime.h>

// DotProductAttention reduced form (verified rounds 1-8, absmax 0.0156):
//   Qeff[q] = 0.7*Q[q-1] + Q[q] + 0.7*Q[q+1]  (zero pad at edges)
//   out[q]  = softmax_{k <= max(q-1,0)}( Qeff[q]·K[k]/8 + beta[k] ) @ V
// Round 13: round-12's regression root-caused by VGPR_Count=84 -- hipcc's
// occupancy heuristic targeted ~6 waves/EU (launch_bounds' 2nd arg is only a
// MINIMUM) and spilled the 64-VGPR prefetch dbuf (WRITE_SIZE 29MB vs 8.4MB
// output = 21MB scratch). Fix: pin amdgpu_waves_per_eu(3,3) -> allocator
// budget 512/3 = 170 VGPR >= ~150 demand -> no spill, still 3 blocks/CU
// (12 waves/CU, LDS 34KB x 3 = 103KB). Kernel body identical to verified
// attn12: grid 1024 = head x q-tile x q-half (long tiles first), 4 waves
// (kh x par), per-wave 32q x 32k x every-2nd tile, barrier-free K-loop,
// 2-barrier 4-way LDS combine. Diagonal mask compile-time specialized.
// Frag store F[hd][tile][frag][lane][8] by cvt8 (unchanged).

typedef short bf16x8 __attribute__((ext_vector_type(8)));
typedef float f32x4  __attribute__((ext_vector_type(4)));

constexpr int S_ = 2048;
constexpr int D_ = 64;
constexpr float LOG2E = 1.44269504088896341f;
constexpr float KSC = 0.125f * LOG2E;   // 1/sqrt(64), log2 domain

template <bool B> struct BC { static constexpr bool v = B; };

// pack two fp32 -> dword of 2 bf16 (round-half-up), lo in low 16
__device__ __forceinline__ unsigned pk2(float lo, float hi) {
    union { float f; unsigned u; } a, b;
    a.f = lo; b.f = hi;
    return __builtin_amdgcn_perm(b.u + 0x8000u, a.u + 0x8000u, 0x07060302u);
}

// ---- fragment pre-swizzle: F[hd][tile][frag][lane][8] bf16 ----
// frag 0..7  = K A-frags  (kh*4 + mb*2 + hh): lane(n,qd) holds
//              K[key = 64t + 32kh + 8(n>>2) + (n&3) + 4mb][d = 32hh + 8qd .. +8]
// frag 8..15 = V^T A-frags (8 + kh*4 + mb): lane(n,qd) holds
//              V[key = 64t + 32kh + 8qd + j][d = 16mb + n], j = 0..7
__global__ __launch_bounds__(256)
void cvt8(const float* __restrict__ K, const float* __restrict__ V,
          unsigned short* __restrict__ F)
{
    __shared__ float T[64][68];   // V^T fp32: [d][key]

    const int bid = blockIdx.x;            // 512: hd = bid&15 -> XCD bid%8 (matches attn)
    const int hd = bid & 15, tt = bid >> 4;
    const float* Kt = K + ((size_t)hd * S_ + tt * 64) * D_;
    const float* Vt = V + ((size_t)hd * S_ + tt * 64) * D_;
    unsigned short* Ft = F + (size_t)(hd * 32 + tt) * 8192;

    const int t = threadIdx.x;
    const int key = t >> 2, d0 = (t & 3) << 4;

    // ---- V: coalesced read -> transposed LDS ----
    {
        const float* vp = Vt + key * D_ + d0;
        #pragma unroll
        for (int i = 0; i < 4; ++i) {
            float4 v4 = *(const float4*)(vp + 4 * i);
            T[d0 + 4 * i + 0][key] = v4.x;
            T[d0 + 4 * i + 1][key] = v4.y;
            T[d0 + 4 * i + 2][key] = v4.z;
            T[d0 + 4 * i + 3][key] = v4.w;
        }
    }

    // ---- K: coalesced read -> direct frag write ----
    {
        const float* kp = Kt + key * D_ + d0;
        float4 a = *(const float4*)(kp);
        float4 b = *(const float4*)(kp + 4);
        float4 c = *(const float4*)(kp + 8);
        float4 d = *(const float4*)(kp + 12);
        uint4 w0 = make_uint4(pk2(a.x, a.y), pk2(a.z, a.w), pk2(b.x, b.y), pk2(b.z, b.w));
        uint4 w1 = make_uint4(pk2(c.x, c.y), pk2(c.z, c.w), pk2(d.x, d.y), pk2(d.z, d.w));
        const int r5 = key & 31;
        const int kh = key >> 5, mb = (r5 >> 2) & 1;
        const int n = ((r5 >> 3) << 2) | (r5 & 3);       // inverse key->M-row perm
        const int hh = d0 >> 5, qd0 = (d0 >> 3) & 3;
        const int f0 = (kh << 2) | (mb << 1) | hh;
        *(uint4*)(Ft + f0 * 512 + ((qd0 << 4) | n) * 8)       = w0;
        *(uint4*)(Ft + f0 * 512 + (((qd0 + 1) << 4) | n) * 8) = w1;
    }
    __syncthreads();

    // ---- V frag emission: contiguous LDS reads, coalesced 16B writes ----
    #pragma unroll
    for (int s = 0; s < 2; ++s) {
        const int slot = t + s * 256;
        const int fr = slot >> 6, lane = slot & 63;
        const int kh = fr >> 2, mb = fr & 3, n = lane & 15, qd = lane >> 4;
        const float* row = &T[mb * 16 + n][kh * 32 + qd * 8];
        uint4 w = make_uint4(pk2(row[0], row[1]), pk2(row[2], row[3]),
                             pk2(row[4], row[5]), pk2(row[6], row[7]));
        *(uint4*)(Ft + (8 + fr) * 512 + lane * 8) = w;
    }
}

__global__ __attribute__((amdgpu_flat_work_group_size(256, 256),
                          amdgpu_waves_per_eu(3, 3)))
void attn13(const float* __restrict__ Q, const float* __restrict__ beta,
            const unsigned short* __restrict__ F, float* __restrict__ out)
{
    __shared__ float slab[3][32][68];   // [wv-1][row][0..63: O, 64: l]
    __shared__ float bl[S_];            // exp-scaled beta (log2 domain)

    const int bid = blockIdx.x;
    const int hd = bid & 15;            // head pinned to XCD bid&7 (2 heads/XCD)
    const int rest = bid >> 4;          // 0..63
    const int j = 31 - (rest >> 1);     // q-tile, longest (j=31) launched first
    const int qh2 = rest & 1;           // which 32-row half of the 64-row tile

    const int q0 = (j << 6) + (qh2 << 5);
    const int nt = j + 1;

    const float* Qh = Q + (size_t)hd * S_ * D_;
    const unsigned short* Fh = F + (size_t)hd * 32 * 8192;

    const int t = threadIdx.x, lane = t & 63;
    const int wv = t >> 6;
    const int kh = wv & 1, par = wv >> 1;   // par 0..1: every-2nd k-tile
    const int n_l = lane & 15, qd = lane >> 4;

    // ---- stage beta*log2e in LDS once (read broadcast by all waves/tiles) ----
    #pragma unroll
    for (int i = 0; i < 8; ++i) bl[t + i * 256] = beta[t + i * 256] * LOG2E;
    __syncthreads();

    // fragment offsets (ushort) within one tile's 8192-ushort block
    const int lo = lane * 8;
    int kfo[2][2], vfo[4];
    #pragma unroll
    for (int mb = 0; mb < 2; ++mb)
        #pragma unroll
        for (int hh = 0; hh < 2; ++hh)
            kfo[mb][hh] = ((kh << 2) | (mb << 1) | hh) * 512 + lo;
    #pragma unroll
    for (int mb = 0; mb < 4; ++mb)
        vfo[mb] = (8 + (kh << 2) + mb) * 512 + lo;

    const int kvo = (kh << 5) + (qd << 3);   // lane's key offset within a tile

    auto ld = [&](int tile, bf16x8 (&ka)[2][2], bf16x8 (&vb)[4]) {
        const unsigned short* fp = Fh + (size_t)tile * 8192;
        ka[0][0] = *(const bf16x8*)(fp + kfo[0][0]);
        ka[0][1] = *(const bf16x8*)(fp + kfo[0][1]);
        ka[1][0] = *(const bf16x8*)(fp + kfo[1][0]);
        ka[1][1] = *(const bf16x8*)(fp + kfo[1][1]);
        #pragma unroll
        for (int mb = 0; mb < 4; ++mb)
            vb[mb] = *(const bf16x8*)(fp + vfo[mb]);
    };

    // ---- Qeff B-fragments from global fp32 Q (two q-rows per lane) ----
    bf16x8 qb[2][2];
    #pragma unroll
    for (int ng = 0; ng < 2; ++ng) {
        const int q = q0 + (ng << 4) + n_l;
        const float wp = (q > 0) ? 0.7f : 0.0f;
        const float wn = (q + 1 < S_) ? 0.7f : 0.0f;
        const float* qc = Qh + (size_t)q * D_;
        const float* qpp = qc - ((q > 0) ? D_ : 0);
        const float* qnn = qc + ((q + 1 < S_) ? D_ : 0);
        #pragma unroll
        for (int hh = 0; hh < 2; ++hh) {
            const int d0 = (hh << 5) + (qd << 3);
            float4 c0 = *(const float4*)(qc + d0),  c1 = *(const float4*)(qc + d0 + 4);
            float4 p0 = *(const float4*)(qpp + d0), p1 = *(const float4*)(qpp + d0 + 4);
            float4 n0 = *(const float4*)(qnn + d0), n1 = *(const float4*)(qnn + d0 + 4);
            float e0 = fmaf(wn, n0.x, fmaf(wp, p0.x, c0.x));
            float e1 = fmaf(wn, n0.y, fmaf(wp, p0.y, c0.y));
            float e2 = fmaf(wn, n0.z, fmaf(wp, p0.z, c0.z));
            float e3 = fmaf(wn, n0.w, fmaf(wp, p0.w, c0.w));
            float e4 = fmaf(wn, n1.x, fmaf(wp, p1.x, c1.x));
            float e5 = fmaf(wn, n1.y, fmaf(wp, p1.y, c1.y));
            float e6 = fmaf(wn, n1.z, fmaf(wp, p1.z, c1.z));
            float e7 = fmaf(wn, n1.w, fmaf(wp, p1.w, c1.w));
            union { unsigned u[4]; bf16x8 v; } qu;
            qu.u[0] = pk2(e0, e1); qu.u[1] = pk2(e2, e3);
            qu.u[2] = pk2(e4, e5); qu.u[3] = pk2(e6, e7);
            qb[ng][hh] = qu.v;
        }
    }

    f32x4 o[4][2];
    float l[2] = {0.0f, 0.0f};
    #pragma unroll
    for (int mb = 0; mb < 4; ++mb)
        #pragma unroll
        for (int ng = 0; ng < 2; ++ng) o[mb][ng] = (f32x4){0, 0, 0, 0};

    auto comp = [&](int tile, bf16x8 (&ka)[2][2], bf16x8 (&vb)[4], auto dmc) {
        constexpr bool DM = decltype(dmc)::v;
        const int kb = (tile << 6) + kvo;
        float4 b0 = *(const float4*)&bl[kb];
        float4 b1 = *(const float4*)&bl[kb + 4];
        const float bt[8] = {b0.x, b0.y, b0.z, b0.w, b1.x, b1.y, b1.z, b1.w};
        const f32x4 zz = {0, 0, 0, 0};
        f32x4 acc[2][2];
        #pragma unroll
        for (int mb = 0; mb < 2; ++mb)
            #pragma unroll
            for (int ng = 0; ng < 2; ++ng) {
                f32x4 a = __builtin_amdgcn_mfma_f32_16x16x32_bf16(ka[mb][0], qb[ng][0], zz, 0, 0, 0);
                acc[mb][ng] = __builtin_amdgcn_mfma_f32_16x16x32_bf16(ka[mb][1], qb[ng][1], a, 0, 0, 0);
            }
        #pragma unroll
        for (int ng = 0; ng < 2; ++ng) {
            float pv[8];
            float la = 0.0f;
            #pragma unroll
            for (int jj = 0; jj < 8; ++jj) {
                const int mb = jj >> 2, r = jj & 3;
                float sv = fmaf(acc[mb][ng][r], KSC, bt[jj]);
                if constexpr (DM) {
                    const int qr = q0 + (ng << 4) + n_l;
                    const int key = kb + jj;
                    if (!((key < qr) || (qr == 0 && key == 0))) sv = -1.0e30f;
                }
                pv[jj] = __builtin_amdgcn_exp2f(sv);
                la += pv[jj];
            }
            l[ng] += la;
            union { unsigned u[4]; bf16x8 v; } pf;
            pf.u[0] = pk2(pv[0], pv[1]);
            pf.u[1] = pk2(pv[2], pv[3]);
            pf.u[2] = pk2(pv[4], pv[5]);
            pf.u[3] = pk2(pv[6], pv[7]);
            #pragma unroll
            for (int mb = 0; mb < 4; ++mb)
                o[mb][ng] = __builtin_amdgcn_mfma_f32_16x16x32_bf16(vb[mb], pf.v, o[mb][ng], 0, 0, 0);
        }
    };

    // ---- barrier-free K-loop over this wave's parity class, 2 buffers ----
    bf16x8 kaA[2][2], vbA[4];
    bf16x8 kaB[2][2], vbB[4];
    int it = par;
    if (it < nt) {
        ld(it, kaA, vbA);
        if (it + 2 < nt) ld(it + 2, kaB, vbB);
        while (it + 4 < nt) {
            comp(it, kaA, vbA, BC<false>{});
            ld(it + 4, kaA, vbA);
            comp(it + 2, kaB, vbB, BC<false>{});
            if (it + 6 < nt) ld(it + 6, kaB, vbB);
            it += 4;
        }
        if (it == nt - 1) comp(it, kaA, vbA, BC<true>{});
        else              comp(it, kaA, vbA, BC<false>{});
        if (it + 2 < nt) {
            if (it + 2 == nt - 1) comp(it + 2, kaB, vbB, BC<true>{});
            else                  comp(it + 2, kaB, vbB, BC<false>{});
        }
    }

    // ---- epilogue: quad-reduce l, 2-barrier 4-way (kh x par) combine ----
    #pragma unroll
    for (int ng = 0; ng < 2; ++ng) {
        l[ng] += __shfl_xor(l[ng], 16);
        l[ng] += __shfl_xor(l[ng], 32);
    }
    if (wv != 0) {
        const int si = wv - 1;
        #pragma unroll
        for (int ng = 0; ng < 2; ++ng) {
            const int row = (ng << 4) + n_l;
            #pragma unroll
            for (int mb = 0; mb < 4; ++mb)
                *(float4*)&slab[si][row][(mb << 4) + (qd << 2)] =
                    make_float4(o[mb][ng][0], o[mb][ng][1], o[mb][ng][2], o[mb][ng][3]);
            if (qd == 0) slab[si][row][64] = l[ng];
        }
    }
    __syncthreads();
    if (wv == 0) {
        #pragma unroll
        for (int ng = 0; ng < 2; ++ng) {
            const int row = (ng << 4) + n_l;
            #pragma unroll
            for (int mb = 0; mb < 4; ++mb) {
                #pragma unroll
                for (int si = 0; si < 3; ++si) {
                    float4 pv4 = *(float4*)&slab[si][row][(mb << 4) + (qd << 2)];
                    o[mb][ng][0] += pv4.x; o[mb][ng][1] += pv4.y;
                    o[mb][ng][2] += pv4.z; o[mb][ng][3] += pv4.w;
                }
            }
            l[ng] += slab[0][row][64] + slab[1][row][64] + slab[2][row][64];
            const float inv = 1.0f / l[ng];
            float* op = out + ((size_t)hd * S_ + q0 + row) * D_ + (qd << 2);
            #pragma unroll
            for (int mb = 0; mb < 4; ++mb)
                *(float4*)(op + (mb << 4)) =
                    make_float4(o[mb][ng][0] * inv, o[mb][ng][1] * inv,
                                o[mb][ng][2] * inv, o[mb][ng][3] * inv);
        }
    }
}

extern "C" void kernel_launch(void* const* d_in, const int* in_sizes, int n_in,
                              void* d_out, int out_size, void* d_ws, size_t ws_size,
                              hipStream_t stream) {
    const float* Q    = (const float*)d_in[0];
    const float* K    = (const float*)d_in[1];
    const float* V    = (const float*)d_in[2];
    const float* beta = (const float*)d_in[3];
    // d_in[4]: causal mask (deterministic triu) — handled analytically in-kernel.
    float* out = (float*)d_out;

    unsigned short* F = (unsigned short*)d_ws;   // 16 hd x 32 t x 16 frag x 512 = 8 MB

    cvt8<<<dim3(512), 256, 0, stream>>>(K, V, F);
    attn13<<<dim3(1024), 256, 0, stream>>>(Q, beta, F, out);
}